// Round 8
// baseline (308.103 us; speedup 1.0000x reference)
//
#include <hip/hip_runtime.h>
#include <hip/hip_bf16.h>

// Shapes: B=2, L=1024, D_MODEL=1024, D_INNER=2048, D_STATE=16, D_CONV=4, DT_RANK=64
#define BATCH 2
#define SEQLEN 1024
#define DMODEL 1024
#define DINNER 2048
#define DSTATE 16
#define DTRANK 64
#define ROWS (BATCH * SEQLEN) // 2048
#define LOG2E 1.44269504088896340736f

using bf16 = __hip_bfloat16;
typedef __bf16 bf16x8 __attribute__((ext_vector_type(8)));
typedef float f32x4 __attribute__((ext_vector_type(4)));
typedef unsigned short us8 __attribute__((ext_vector_type(8)));

__device__ __forceinline__ float to_f(float x) { return x; }
__device__ __forceinline__ float to_f(bf16 x) { return __bfloat162float(x); }

__device__ __forceinline__ float fexp2(float x) { return __builtin_amdgcn_exp2f(x); }

__device__ __forceinline__ float bfu(unsigned short u) {
    union { unsigned int i; float f; } v;
    v.i = ((unsigned int)u) << 16;
    return v.f;
}

__device__ __forceinline__ unsigned short bf_bits(float x) {
    bf16 h = __float2bfloat16(x);
    union { bf16 b; unsigned short u; } cv;
    cv.b = h;
    return cv.u;
}

__device__ __forceinline__ float softplus_f(float x) {
    return fmaxf(x, 0.f) + log1pf(expf(-fabsf(x)));
}
// fast silu
__device__ __forceinline__ float silu_f(float x) {
    return x * __builtin_amdgcn_rcpf(1.f + fexp2(-x * LOG2E));
}

// DPP row_shr move (within 16-lane row); invalid source lanes contribute 0.
template <int CTRL>
__device__ __forceinline__ float dpp_shr(float x) {
    int r = __builtin_amdgcn_update_dpp(0, __builtin_bit_cast(int, x), CTRL, 0xF, 0xF, false);
    return __builtin_bit_cast(float, r);
}
// 16-lane reduce: lane (n==15) of each row16 holds the sum.
__device__ __forceinline__ float row16_sum_to_lane15(float p) {
    p += dpp_shr<0x111>(p);  // row_shr:1
    p += dpp_shr<0x112>(p);  // row_shr:2
    p += dpp_shr<0x114>(p);  // row_shr:4
    p += dpp_shr<0x118>(p);  // row_shr:8
    return p;
}

// async 16B global -> LDS
__device__ __forceinline__ void gload16(const void* g, void* l) {
    __builtin_amdgcn_global_load_lds(
        (const __attribute__((address_space(1))) void*)g,
        (__attribute__((address_space(3))) void*)l, 16, 0, 0);
}

// ---------- prep: block 0 = dtype detect; blocks 1.. zero xd ----------
__global__ __launch_bounds__(256) void prep_kernel(const unsigned short* hs, int* flag,
                                                   float* zbuf, int nzero) {
    if (blockIdx.x == 0) {
        __shared__ int cnt[256];
        int c = 0;
        for (int i = threadIdx.x; i < 8192; i += 256) {
            int e = (hs[i] >> 7) & 0xFF;
            if (e == 0 || e == 0xFF || e < 96 || e > 159) c++;
        }
        cnt[threadIdx.x] = c;
        __syncthreads();
        for (int s = 128; s > 0; s >>= 1) {
            if (threadIdx.x < s) cnt[threadIdx.x] += cnt[threadIdx.x + s];
            __syncthreads();
        }
        if (threadIdx.x == 0) *flag = (cnt[0] < 512) ? 1 : 0;
    } else {
        int i = (blockIdx.x - 1) * 256 + threadIdx.x;
        if (i < nzero) zbuf[i] = 0.f;
    }
}

// ---------- fused convert; big bf16 segments skipped (read direct) ----------
struct SrcPtrs { const void* p[10]; };

__device__ __constant__ const size_t SEG_OFF[11] = {
    0, 2097152, 6291456, 6299648, 6301696, 6498304,
    6629376, 6631424, 6664192, 6666240, 8763392
};

__global__ __launch_bounds__(256) void convert_all(SrcPtrs s, bf16* __restrict__ dst,
                                                   const int* __restrict__ flag) {
    size_t e = ((size_t)blockIdx.x * 256 + threadIdx.x) * 4;
    if (e >= SEG_OFF[10]) return;
    int seg = 0;
    #pragma unroll
    for (int i = 1; i < 10; ++i) if (e >= SEG_OFF[i]) seg = i;
    int isbf = *flag;
    if (isbf && (seg == 0 || seg == 1 || seg == 9)) return;
    size_t loc = e - SEG_OFF[seg];
    if (isbf) {
        ushort4 v = ((const ushort4*)s.p[seg])[loc / 4];
        ((ushort4*)(dst + e))[0] = v;
    } else {
        float4 v = ((const float4*)s.p[seg])[loc / 4];
        ushort4 o;
        o.x = bf_bits(v.x); o.y = bf_bits(v.y);
        o.z = bf_bits(v.z); o.w = bf_bits(v.w);
        ((ushort4*)(dst + e))[0] = o;
    }
}

// ---------------- MFMA GEMM: C[m][n] = sum_k A[m][k]*B[n][k], bf16 in, 128x128 tile ----
// OUTMODE: 0 = bf16 store; 2 = f32 split-K partials; 3 = f32 atomicAdd col<96;
//          4 = f32 softplus(v + bias[row])
template <int OUTMODE>
__global__ __launch_bounds__(256) void gemm_mfma(
    const bf16* __restrict__ A, int lda,
    const bf16* __restrict__ Bm, int ldb,
    void* __restrict__ C, int ldc,
    int Kspl, size_t pstride,
    const bf16* __restrict__ bias,
    const bf16* __restrict__ Aalt,
    const bf16* __restrict__ Balt,
    const int* __restrict__ flag)
{
    if (flag && *flag) {
        if (Aalt) A = Aalt;
        if (Balt) Bm = Balt;
    }
    __shared__ __align__(16) __bf16 sA[128 * 32];
    __shared__ __align__(16) __bf16 sB[128 * 32];
    const int tid = threadIdx.x;
    const int m0 = blockIdx.y * 128;
    const int n0 = blockIdx.x * 128;
    const int wid = tid >> 6, ln = tid & 63;
    const int wy = (wid >> 1) * 64, wx = (wid & 1) * 64;
    const int q = ln >> 4, m16 = ln & 15;
    const int kbeg = blockIdx.z * Kspl;

    f32x4 acc[4][4] = {};

    for (int k0 = kbeg; k0 < kbeg + Kspl; k0 += 32) {
        #pragma unroll
        for (int i = 0; i < 2; ++i) {
            int idx = tid + i * 256;
            int r = idx >> 2, c = (idx & 3) * 8;
            gload16(&A[(size_t)(m0 + r) * lda + k0 + c], &sA[idx * 8]);
        }
        #pragma unroll
        for (int i = 0; i < 2; ++i) {
            int idx = tid + i * 256;
            int r = idx >> 2, c = (idx & 3) * 8;
            gload16(&Bm[(size_t)(n0 + r) * ldb + k0 + c], &sB[idx * 8]);
        }
        __syncthreads();
        bf16x8 a[4], b[4];
        #pragma unroll
        for (int i = 0; i < 4; ++i)
            a[i] = *(const bf16x8*)&sA[(wy + i * 16 + m16) * 32 + q * 8];
        #pragma unroll
        for (int j = 0; j < 4; ++j)
            b[j] = *(const bf16x8*)&sB[(wx + j * 16 + m16) * 32 + q * 8];
        #pragma unroll
        for (int i = 0; i < 4; ++i)
            #pragma unroll
            for (int j = 0; j < 4; ++j)
                acc[i][j] = __builtin_amdgcn_mfma_f32_16x16x32_bf16(a[i], b[j], acc[i][j], 0, 0, 0);
        __syncthreads();
    }

    #pragma unroll
    for (int i = 0; i < 4; ++i) {
        #pragma unroll
        for (int j = 0; j < 4; ++j) {
            #pragma unroll
            for (int r = 0; r < 4; ++r) {
                int row = m0 + wy + i * 16 + q * 4 + r;
                int col = n0 + wx + j * 16 + m16;
                size_t idx = (size_t)row * ldc + col;
                float v = acc[i][j][r];
                if constexpr (OUTMODE == 0) {
                    ((bf16*)C)[idx] = __float2bfloat16(v);
                } else if constexpr (OUTMODE == 2) {
                    ((float*)C + blockIdx.z * pstride)[idx] = v;
                } else if constexpr (OUTMODE == 3) {
                    if (col < 96) atomicAdd((float*)C + idx, v);
                } else if constexpr (OUTMODE == 4) {
                    ((float*)C)[idx] = softplus_f(v + to_f(bias[row]));
                }
            }
        }
    }
}

// sum the two split-K partials, store to d_out as bf16 or f32 per flag
__global__ __launch_bounds__(256) void sum_store(
    const float* __restrict__ p0, const float* __restrict__ p1,
    void* __restrict__ out, const int* __restrict__ flag, int n4)
{
    int i = blockIdx.x * 256 + threadIdx.x;
    if (i >= n4) return;
    float4 a = ((const float4*)p0)[i];
    float4 b = ((const float4*)p1)[i];
    float4 sv; sv.x = a.x + b.x; sv.y = a.y + b.y; sv.z = a.z + b.z; sv.w = a.w + b.w;
    if (*flag) {
        ushort4 o;
        o.x = bf_bits(sv.x); o.y = bf_bits(sv.y);
        o.z = bf_bits(sv.z); o.w = bf_bits(sv.w);
        ((ushort4*)out)[i] = o;
    } else {
        ((float4*)out)[i] = sv;
    }
}

// ---------------- transpose (d,row) -> (row,d), 64x64 LDS tiles ----------------
__global__ __launch_bounds__(256) void transpose_bf16(
    const ushort* __restrict__ src,   // (DINNER, ROWS)
    ushort* __restrict__ dst)         // (ROWS, DINNER)
{
    __shared__ ushort t[64][65];
    const int bx = blockIdx.x;        // row-tile
    const int by = blockIdx.y;        // d-tile
    const int tid = threadIdx.x;
    const int lr = tid & 63;
    const int ld = tid >> 6;          // 0..3
    #pragma unroll
    for (int i = 0; i < 16; ++i) {
        int d = ld + i * 4;
        t[d][lr] = src[(size_t)(by * 64 + d) * ROWS + bx * 64 + lr];
    }
    __syncthreads();
    #pragma unroll
    for (int i = 0; i < 16; ++i) {
        int r = ld + i * 4;
        dst[(size_t)(bx * 64 + r) * DINNER + by * 64 + lr] = t[lr][r];
    }
}

// ---------------- xd cvt: xd (2048,96) f32 -> xd_bf bf16 (row-major) ----------------
__global__ __launch_bounds__(256) void xd_cvt(
    const float* __restrict__ xd,
    bf16* __restrict__ xd_bf)
{
    int i = blockIdx.x * 256 + threadIdx.x;   // float4 index; grid sized exactly
    float4 v = ((const float4*)xd)[i];
    ushort4 o;
    o.x = bf_bits(v.x); o.y = bf_bits(v.y);
    o.z = bf_bits(v.z); o.w = bf_bits(v.w);
    ((ushort4*)xd_bf)[i] = o;
}

// ---------------- fused conv+silu+transpose: xzT -> utT (d-major) AND ut (row-major) ----
// 64x64 tile per block: grid (ROWS/64, DINNER/64). Stage xzT tile (+4-col halo)
// in LDS, compute the causal depthwise conv + silu once, write utT coalesced,
// stage results in a [64][65] LDS tile, write ut coalesced. Replaces the old
// conv_silu_T8 + transpose_bf16 pair: one pass over the data instead of two
// (42 MB -> 33.6 MB traffic, one fewer launch). Conv math bit-identical.
__global__ __launch_bounds__(256) void conv_silu_fused(
    const bf16* __restrict__ xzT,   // (4096, ROWS); x part rows 0..DINNER-1
    const bf16* __restrict__ w,     // (DINNER, 4)
    const bf16* __restrict__ bias,  // (DINNER,)
    bf16* __restrict__ utT,         // (DINNER, ROWS)
    ushort* __restrict__ ut)        // (ROWS, DINNER)
{
    __shared__ ushort sx[64][68];   // [d-local][r-local+4 halo]
    __shared__ ushort tt[64][65];   // staged outputs for the transpose write
    const int bx = blockIdx.x;      // r tile
    const int by = blockIdx.y;      // d tile
    const int tid = threadIdx.x;
    const int gr0 = bx * 64;
    const bool seqstart = (bx & 15) == 0;   // tile starts a sequence (r0 = 0 or 1024)

    // load 64 rows x 17 ushort4 chunks (cols gr0-4 .. gr0+63)
    for (int idx = tid; idx < 64 * 17; idx += 256) {
        int row = idx / 17;
        int c = idx - row * 17;
        ushort4 v;
        if (c == 0 && seqstart) {
            v.x = v.y = v.z = v.w = 0;   // pre-sequence halo = 0 (no OOB read)
        } else {
            const ushort* src = (const ushort*)xzT +
                (size_t)(by * 64 + row) * ROWS + (gr0 - 4 + c * 4);
            v = *(const ushort4*)src;
        }
        *(ushort4*)&sx[row][c * 4] = v;
    }
    __syncthreads();

    const int lr = tid & 63;        // r-local (per-lane)
    const int ld = tid >> 6;        // wave id 0..3 (wave-uniform)
    #pragma unroll
    for (int i = 0; i < 16; ++i) {
        int dl = ld + i * 4;        // wave-uniform d-local
        int dg = by * 64 + dl;
        ushort4 wv = *(const ushort4*)((const ushort*)w + dg * 4);  // scalarized
        float w0 = bfu(wv.x), w1 = bfu(wv.y), w2 = bfu(wv.z), w3 = bfu(wv.w);
        float bv = to_f(bias[dg]);
        float acc = bv;
        acc = fmaf(bfu(sx[dl][lr + 1]), w0, acc);   // x[r-3]
        acc = fmaf(bfu(sx[dl][lr + 2]), w1, acc);   // x[r-2]
        acc = fmaf(bfu(sx[dl][lr + 3]), w2, acc);   // x[r-1]
        acc = fmaf(bfu(sx[dl][lr + 4]), w3, acc);   // x[r]
        ushort o = bf_bits(silu_f(acc));
        ((ushort*)utT)[(size_t)dg * ROWS + gr0 + lr] = o;
        tt[dl][lr] = o;
    }
    __syncthreads();
    #pragma unroll
    for (int i = 0; i < 16; ++i) {
        int rl = ld + i * 4;
        ut[(size_t)(gr0 + rl) * DINNER + by * 64 + lr] = tt[lr][rl];
    }
}

// ---------------- scan v16: cheap-pass / full-pass, 512-thr wave-uniform chunks ----
// (proven 81.6 us in R6; R7's deeper prefetch regressed -> reverted verbatim)
#define SCHUNK 8
#define SSTEPS (SEQLEN / SCHUNK)   // 128
__global__ __launch_bounds__(512) void scan_kernel16(
    const float* __restrict__ deltaT,  // (DINNER, ROWS) f32
    const bf16*  __restrict__ utT,     // (DINNER, ROWS)
    const float* __restrict__ xd96,    // (ROWS, 96) f32: col 64+n = B_n, 80+n = C_n
    const bf16*  __restrict__ xzT,     // (4096, ROWS): z at row DINNER+d
    const bf16*  __restrict__ A_log,   // (DINNER,16)
    const bf16*  __restrict__ Dp,      // (DINNER,)
    bf16* __restrict__ outzT)          // (DINNER, ROWS)
{
    __shared__ float2 sHP[SCHUNK][64];
    const int tid = threadIdx.x;
    const int c = tid >> 6;            // wave-uniform chunk id 0..7
    const int w = tid & 63;
    const int dcol = (tid >> 4) & 3;
    const int n = tid & 15;
    const int b = blockIdx.x >> 9;
    const int d = ((blockIdx.x & 511) << 2) + dcol;
    const int row0 = b * SEQLEN + c * SSTEPS;

    const float Aa2 = -expf(to_f(A_log[d * DSTATE + n])) * LOG2E;
    const float Dv = to_f(Dp[d]);

    const float*  dp = deltaT + (size_t)d * ROWS + row0;
    const ushort* up = (const ushort*)utT + (size_t)d * ROWS + row0;
    const ushort* zp = (const ushort*)xzT + (size_t)(DINNER + d) * ROWS + row0;
    const float*  bcp = xd96 + (size_t)row0 * 96 + 64 + n;  // B at +0, C at +16

    // ---- pass A: chunk summary only (h-chain + sum of delta) ----
    // NOTE: dv/uv last-iteration prefetch reads 16B past the logical chunk;
    // all streams are interior workspace regions followed by more workspace,
    // so the over-read stays inside d_ws and the values are never used.
    float hl = 0.f, sd = 0.f;
    float4  dv4 = *(const float4*)(dp);
    ushort4 uv4 = *(const ushort4*)(up);
    const float* bct = bcp;
    for (int i0 = 0; i0 < SSTEPS; i0 += 4) {
        float4  dvn = *(const float4*)(dp + i0 + 4);
        ushort4 uvn = *(const ushort4*)(up + i0 + 4);
        float Bv[4];
        Bv[0] = bct[0];
        Bv[1] = bct[96];
        Bv[2] = bct[192];
        Bv[3] = bct[288];
        bct += 384;
        float dv[4] = {dv4.x, dv4.y, dv4.z, dv4.w};
        float uv[4] = {bfu(uv4.x), bfu(uv4.y), bfu(uv4.z), bfu(uv4.w)};
        #pragma unroll
        for (int j = 0; j < 4; ++j) {
            sd += dv[j];
            float a = fexp2(dv[j] * Aa2);
            hl = fmaf(a, hl, dv[j] * Bv[j] * uv[j]);
        }
        dv4 = dvn; uv4 = uvn;
    }
    sHP[c][w] = make_float2(hl, fexp2(sd * Aa2));
    __syncthreads();

    // ---- fold preceding chunk summaries (<= 7 iters, wave-uniform) ----
    float hin = 0.f;
    for (int cc = 0; cc < c; ++cc) {
        float2 hp = sHP[cc][w];
        hin = fmaf(hp.y, hin, hp.x);
    }

    // ---- pass B: full rescan seeded with hin; y produced directly ----
    float h = hin;
    dv4 = *(const float4*)(dp);
    uv4 = *(const ushort4*)(up);
    ushort4 zv4 = *(const ushort4*)(zp);
    bct = bcp;
    for (int i0 = 0; i0 < SSTEPS; i0 += 4) {
        float4  dvn = *(const float4*)(dp + i0 + 4);
        ushort4 uvn = *(const ushort4*)(up + i0 + 4);
        ushort4 zvn = *(const ushort4*)(zp + i0 + 4);
        float Bv[4], Cv[4];
        Bv[0] = bct[0];   Cv[0] = bct[16];
        Bv[1] = bct[96];  Cv[1] = bct[112];
        Bv[2] = bct[192]; Cv[2] = bct[208];
        Bv[3] = bct[288]; Cv[3] = bct[304];
        bct += 384;
        float dv[4] = {dv4.x, dv4.y, dv4.z, dv4.w};
        float uv[4] = {bfu(uv4.x), bfu(uv4.y), bfu(uv4.z), bfu(uv4.w)};
        float zv[4] = {bfu(zv4.x), bfu(zv4.y), bfu(zv4.z), bfu(zv4.w)};
        float y[4];
        #pragma unroll
        for (int j = 0; j < 4; ++j) {
            float a = fexp2(dv[j] * Aa2);
            h = fmaf(a, h, dv[j] * Bv[j] * uv[j]);
            float p = h * Cv[j];
            p = row16_sum_to_lane15(p);
            y[j] = fmaf(uv[j], Dv, p);
        }
        if (n == 15) {
            ushort4 o;
            o.x = bf_bits(y[0] * silu_f(zv[0]));
            o.y = bf_bits(y[1] * silu_f(zv[1]));
            o.z = bf_bits(y[2] * silu_f(zv[2]));
            o.w = bf_bits(y[3] * silu_f(zv[3]));
            *(ushort4*)((ushort*)outzT + (size_t)d * ROWS + row0 + i0) = o;
        }
        dv4 = dvn; uv4 = uvn; zv4 = zvn;
    }
}

extern "C" void kernel_launch(void* const* d_in, const int* in_sizes, int n_in,
                              void* d_out, int out_size, void* d_ws, size_t ws_size,
                              hipStream_t stream) {
    static const size_t SZ[10] = {
        (size_t)BATCH * SEQLEN * DMODEL,        // hidden_states
        (size_t)2 * DINNER * DMODEL,            // in_proj_w
        (size_t)DINNER * 4,                     // conv1d_w
        (size_t)DINNER,                         // conv1d_b
        (size_t)(DTRANK + 2 * DSTATE) * DINNER, // x_proj_w
        (size_t)DINNER * DTRANK,                // dt_proj_w
        (size_t)DINNER,                         // dt_proj_b
        (size_t)DINNER * DSTATE,                // A_log
        (size_t)DINNER,                         // D_param
        (size_t)DMODEL * DINNER                 // out_proj_w
    };
    size_t tot_in = 0;
    for (int i = 0; i < 10; ++i) tot_in += SZ[i];

    char* p = (char*)d_ws;
    int* flag = (int*)p;                     p += 64;
    bf16* inb = (bf16*)p;                    p += tot_in * 2;
    bf16* xzT = (bf16*)p;                    p += (size_t)4096 * ROWS * 2;
    bf16* utT = (bf16*)p;                    p += (size_t)DINNER * ROWS * 2;
    bf16* ut  = (bf16*)p;                    p += (size_t)ROWS * DINNER * 2;
    float* xd = (float*)p;                   p += (size_t)ROWS * 96 * 4;
    bf16* xd_bf = (bf16*)p;                  p += (size_t)ROWS * 96 * 2;
    float* deltaT = (float*)p;               p += (size_t)DINNER * ROWS * 4;
    bf16* outzT = (bf16*)p;                  p += (size_t)DINNER * ROWS * 2;
    bf16* outz = (bf16*)p;                   p += (size_t)ROWS * DINNER * 2;
    float* part = (float*)p;                 p += (size_t)2 * ROWS * DMODEL * 4;
    size_t needed = (size_t)(p - (char*)d_ws);
    if (ws_size < needed) return;

    dim3 blk(256);

    // 0) detect dtype + zero xd (for atomic accumulation)
    prep_kernel<<<1 + (ROWS * 96 + 255) / 256, blk, 0, stream>>>(
        (const unsigned short*)d_in[0], flag, xd, ROWS * 96);

    bf16* inp[10];
    {
        size_t off = 0;
        for (int i = 0; i < 10; ++i) { inp[i] = inb + off; off += SZ[i]; }
    }
    SrcPtrs sp;
    for (int i = 0; i < 10; ++i) sp.p[i] = d_in[i];
    convert_all<<<(int)((tot_in / 4 + 255) / 256), blk, 0, stream>>>(sp, inb, flag);

    const bf16* hs        = inp[0];
    const bf16* in_proj_w = inp[1];
    const bf16* conv_w    = inp[2];
    const bf16* conv_b    = inp[3];
    const bf16* x_proj_w  = inp[4];
    const bf16* dt_proj_w = inp[5];
    const bf16* dt_proj_b = inp[6];
    const bf16* A_log     = inp[7];
    const bf16* Dp        = inp[8];
    const bf16* out_proj_w= inp[9];

    // 1) xzT = (hs @ in_proj_w^T)^T : dual-ptr — reads d_in directly when bf16
    gemm_mfma<0><<<dim3(ROWS / 128, 4096 / 128, 1), blk, 0, stream>>>(
        in_proj_w, DMODEL, hs, DMODEL, xzT, ROWS, DMODEL, 0, nullptr,
        (const bf16*)d_in[1], (const bf16*)d_in[0], flag);

    // 2) fused: utT = silu(causal conv along L) AND ut = utT^T, one pass
    conv_silu_fused<<<dim3(ROWS / 64, DINNER / 64), blk, 0, stream>>>(
        xzT, conv_w, conv_b, utT, (ushort*)ut);

    // 3) xd[row][r] = sum_d ut[row][d] * x_proj_w[r][d]  (MFMA, split-K=4, atomic f32)
    gemm_mfma<3><<<dim3(1, ROWS / 128, 4), blk, 0, stream>>>(
        ut, DINNER, x_proj_w, DINNER, xd, 96, DINNER / 4, 0, nullptr,
        nullptr, nullptr, nullptr);

    // 3b) xd_bf = bf16(xd)  (row-major, dt GEMM operand); scan reads xd directly
    xd_cvt<<<ROWS * 96 / 4 / 256, blk, 0, stream>>>(xd, xd_bf);

    // 4) deltaT[d][row] = softplus(sum_r dtw[d][r]*xd[row][r] + dtb[d])  (MFMA K=64)
    gemm_mfma<4><<<dim3(ROWS / 128, DINNER / 128, 1), blk, 0, stream>>>(
        dt_proj_w, DTRANK, xd_bf, 96, deltaT, ROWS, DTRANK, 0, dt_proj_b,
        nullptr, nullptr, nullptr);

    // 5) chunk-parallel selective scan -> outzT (d-major, full-line writes)
    scan_kernel16<<<BATCH * (DINNER / 4), dim3(512), 0, stream>>>(
        deltaT, utT, xd, xzT, A_log, Dp, outzT);

    // 5b) outz = outzT^T (row-major for gemm6)
    transpose_bf16<<<dim3(ROWS / 64, DINNER / 64), blk, 0, stream>>>(
        (const ushort*)outzT, (ushort*)outz);

    // 6) out = outz @ out_proj_w^T  (MFMA split-K=2 -> f32 partials; dual-ptr B)
    gemm_mfma<2><<<dim3(DMODEL / 128, ROWS / 128, 2), blk, 0, stream>>>(
        outz, DINNER, out_proj_w, DINNER, part, DMODEL, DINNER / 2, (size_t)ROWS * DMODEL,
        nullptr, nullptr, (const bf16*)d_in[9], flag);

    // 6b) out = cvt(part0 + part1)
    sum_store<<<(ROWS * DMODEL / 4 + 255) / 256, blk, 0, stream>>>(
        part, part + (size_t)ROWS * DMODEL, d_out, flag, ROWS * DMODEL / 4);
}

// Round 9
// 287.167 us; speedup vs baseline: 1.0729x; 1.0729x over previous
//
#include <hip/hip_runtime.h>
#include <hip/hip_bf16.h>

// Shapes: B=2, L=1024, D_MODEL=1024, D_INNER=2048, D_STATE=16, D_CONV=4, DT_RANK=64
#define BATCH 2
#define SEQLEN 1024
#define DMODEL 1024
#define DINNER 2048
#define DSTATE 16
#define DTRANK 64
#define ROWS (BATCH * SEQLEN) // 2048
#define LOG2E 1.44269504088896340736f

using bf16 = __hip_bfloat16;
typedef __bf16 bf16x8 __attribute__((ext_vector_type(8)));
typedef float f32x4 __attribute__((ext_vector_type(4)));
typedef unsigned short us8 __attribute__((ext_vector_type(8)));

__device__ __forceinline__ float to_f(float x) { return x; }
__device__ __forceinline__ float to_f(bf16 x) { return __bfloat162float(x); }

__device__ __forceinline__ float fexp2(float x) { return __builtin_amdgcn_exp2f(x); }

__device__ __forceinline__ float bfu(unsigned short u) {
    union { unsigned int i; float f; } v;
    v.i = ((unsigned int)u) << 16;
    return v.f;
}

__device__ __forceinline__ unsigned short bf_bits(float x) {
    bf16 h = __float2bfloat16(x);
    union { bf16 b; unsigned short u; } cv;
    cv.b = h;
    return cv.u;
}

__device__ __forceinline__ float softplus_f(float x) {
    return fmaxf(x, 0.f) + log1pf(expf(-fabsf(x)));
}
// fast silu
__device__ __forceinline__ float silu_f(float x) {
    return x * __builtin_amdgcn_rcpf(1.f + fexp2(-x * LOG2E));
}

// DPP row_shr move (within 16-lane row); invalid source lanes contribute 0.
template <int CTRL>
__device__ __forceinline__ float dpp_shr(float x) {
    int r = __builtin_amdgcn_update_dpp(0, __builtin_bit_cast(int, x), CTRL, 0xF, 0xF, false);
    return __builtin_bit_cast(float, r);
}
// 16-lane reduce: lane (n==15) of each row16 holds the sum.
__device__ __forceinline__ float row16_sum_to_lane15(float p) {
    p += dpp_shr<0x111>(p);  // row_shr:1
    p += dpp_shr<0x112>(p);  // row_shr:2
    p += dpp_shr<0x114>(p);  // row_shr:4
    p += dpp_shr<0x118>(p);  // row_shr:8
    return p;
}

// async 16B global -> LDS
__device__ __forceinline__ void gload16(const void* g, void* l) {
    __builtin_amdgcn_global_load_lds(
        (const __attribute__((address_space(1))) void*)g,
        (__attribute__((address_space(3))) void*)l, 16, 0, 0);
}

// ---------- prep: block 0 = dtype detect; blocks 1.. zero xd ----------
__global__ __launch_bounds__(256) void prep_kernel(const unsigned short* hs, int* flag,
                                                   float* zbuf, int nzero) {
    if (blockIdx.x == 0) {
        __shared__ int cnt[256];
        int c = 0;
        for (int i = threadIdx.x; i < 8192; i += 256) {
            int e = (hs[i] >> 7) & 0xFF;
            if (e == 0 || e == 0xFF || e < 96 || e > 159) c++;
        }
        cnt[threadIdx.x] = c;
        __syncthreads();
        for (int s = 128; s > 0; s >>= 1) {
            if (threadIdx.x < s) cnt[threadIdx.x] += cnt[threadIdx.x + s];
            __syncthreads();
        }
        if (threadIdx.x == 0) *flag = (cnt[0] < 512) ? 1 : 0;
    } else {
        int i = (blockIdx.x - 1) * 256 + threadIdx.x;
        if (i < nzero) zbuf[i] = 0.f;
    }
}

// ---------- fused convert; big bf16 segments skipped (read direct) ----------
struct SrcPtrs { const void* p[10]; };

__device__ __constant__ const size_t SEG_OFF[11] = {
    0, 2097152, 6291456, 6299648, 6301696, 6498304,
    6629376, 6631424, 6664192, 6666240, 8763392
};

__global__ __launch_bounds__(256) void convert_all(SrcPtrs s, bf16* __restrict__ dst,
                                                   const int* __restrict__ flag) {
    size_t e = ((size_t)blockIdx.x * 256 + threadIdx.x) * 4;
    if (e >= SEG_OFF[10]) return;
    int seg = 0;
    #pragma unroll
    for (int i = 1; i < 10; ++i) if (e >= SEG_OFF[i]) seg = i;
    int isbf = *flag;
    if (isbf && (seg == 0 || seg == 1 || seg == 9)) return;
    size_t loc = e - SEG_OFF[seg];
    if (isbf) {
        ushort4 v = ((const ushort4*)s.p[seg])[loc / 4];
        ((ushort4*)(dst + e))[0] = v;
    } else {
        float4 v = ((const float4*)s.p[seg])[loc / 4];
        ushort4 o;
        o.x = bf_bits(v.x); o.y = bf_bits(v.y);
        o.z = bf_bits(v.z); o.w = bf_bits(v.w);
        ((ushort4*)(dst + e))[0] = o;
    }
}

// ---------------- MFMA GEMM: C[m][n] = sum_k A[m][k]*B[n][k], bf16 in, 128x128 tile ----
// OUTMODE: 0 = bf16 store; 2 = f32 split-K partials; 3 = f32 atomicAdd col<96;
//          4 = f32 softplus(v + bias[row])
template <int OUTMODE>
__global__ __launch_bounds__(256) void gemm_mfma(
    const bf16* __restrict__ A, int lda,
    const bf16* __restrict__ Bm, int ldb,
    void* __restrict__ C, int ldc,
    int Kspl, size_t pstride,
    const bf16* __restrict__ bias,
    const bf16* __restrict__ Aalt,
    const bf16* __restrict__ Balt,
    const int* __restrict__ flag)
{
    if (flag && *flag) {
        if (Aalt) A = Aalt;
        if (Balt) Bm = Balt;
    }
    __shared__ __align__(16) __bf16 sA[128 * 32];
    __shared__ __align__(16) __bf16 sB[128 * 32];
    const int tid = threadIdx.x;
    const int m0 = blockIdx.y * 128;
    const int n0 = blockIdx.x * 128;
    const int wid = tid >> 6, ln = tid & 63;
    const int wy = (wid >> 1) * 64, wx = (wid & 1) * 64;
    const int q = ln >> 4, m16 = ln & 15;
    const int kbeg = blockIdx.z * Kspl;

    f32x4 acc[4][4] = {};

    for (int k0 = kbeg; k0 < kbeg + Kspl; k0 += 32) {
        #pragma unroll
        for (int i = 0; i < 2; ++i) {
            int idx = tid + i * 256;
            int r = idx >> 2, c = (idx & 3) * 8;
            gload16(&A[(size_t)(m0 + r) * lda + k0 + c], &sA[idx * 8]);
        }
        #pragma unroll
        for (int i = 0; i < 2; ++i) {
            int idx = tid + i * 256;
            int r = idx >> 2, c = (idx & 3) * 8;
            gload16(&Bm[(size_t)(n0 + r) * ldb + k0 + c], &sB[idx * 8]);
        }
        __syncthreads();
        bf16x8 a[4], b[4];
        #pragma unroll
        for (int i = 0; i < 4; ++i)
            a[i] = *(const bf16x8*)&sA[(wy + i * 16 + m16) * 32 + q * 8];
        #pragma unroll
        for (int j = 0; j < 4; ++j)
            b[j] = *(const bf16x8*)&sB[(wx + j * 16 + m16) * 32 + q * 8];
        #pragma unroll
        for (int i = 0; i < 4; ++i)
            #pragma unroll
            for (int j = 0; j < 4; ++j)
                acc[i][j] = __builtin_amdgcn_mfma_f32_16x16x32_bf16(a[i], b[j], acc[i][j], 0, 0, 0);
        __syncthreads();
    }

    #pragma unroll
    for (int i = 0; i < 4; ++i) {
        #pragma unroll
        for (int j = 0; j < 4; ++j) {
            #pragma unroll
            for (int r = 0; r < 4; ++r) {
                int row = m0 + wy + i * 16 + q * 4 + r;
                int col = n0 + wx + j * 16 + m16;
                size_t idx = (size_t)row * ldc + col;
                float v = acc[i][j][r];
                if constexpr (OUTMODE == 0) {
                    ((bf16*)C)[idx] = __float2bfloat16(v);
                } else if constexpr (OUTMODE == 2) {
                    ((float*)C + blockIdx.z * pstride)[idx] = v;
                } else if constexpr (OUTMODE == 3) {
                    if (col < 96) atomicAdd((float*)C + idx, v);
                } else if constexpr (OUTMODE == 4) {
                    ((float*)C)[idx] = softplus_f(v + to_f(bias[row]));
                }
            }
        }
    }
}

// ---------------- dt_gemm: deltaT[d][row] = softplus(dot64(dtw[d], xd[row]) + b[d]) ----
// Custom skinny-K GEMM (K=64): 16x16 MFMA tiles, NO LDS, NO barriers, direct
// global->fragment loads (A frag: lane reads dtw[m0+(ln&15)][(ln>>4)*8..+8] =
// one 16B load; same fragment layout the 128x128 template uses from LDS).
// Grid (ROWS/16, DINNER/64) = 4096 blocks x 4 waves = 16K waves (vs the
// template's 256 blocks / 11% occupancy / 101us). dtw (256KB) and xd_bf
// (384KB) are L2-resident. Math order identical to OUTMODE 4 (two MFMAs).
__global__ __launch_bounds__(256) void dt_gemm(
    const bf16* __restrict__ dtw,    // (DINNER, 64) row-major
    const bf16* __restrict__ xdb,    // (ROWS, 96) row-major; cols 0..63 = dt_low
    const bf16* __restrict__ bias,   // (DINNER,)
    float* __restrict__ deltaT)      // (DINNER, ROWS)
{
    const int tid = threadIdx.x;
    const int wid = tid >> 6, ln = tid & 63;
    const int q = ln >> 4, m16 = ln & 15;
    const int n0 = blockIdx.x * 16;              // L-row tile
    const int m0 = (blockIdx.y * 4 + wid) * 16;  // d tile (per wave)

    const ushort* ap = (const ushort*)dtw + (size_t)(m0 + m16) * 64 + q * 8;
    bf16x8 a0 = *(const bf16x8*)(ap);
    bf16x8 a1 = *(const bf16x8*)(ap + 32);
    const ushort* bp = (const ushort*)xdb + (size_t)(n0 + m16) * 96 + q * 8;
    bf16x8 b0 = *(const bf16x8*)(bp);
    bf16x8 b1 = *(const bf16x8*)(bp + 32);

    f32x4 acc = {};
    acc = __builtin_amdgcn_mfma_f32_16x16x32_bf16(a0, b0, acc, 0, 0, 0);
    acc = __builtin_amdgcn_mfma_f32_16x16x32_bf16(a1, b1, acc, 0, 0, 0);

    const int d0 = m0 + q * 4;
    ushort4 bb = *(const ushort4*)((const ushort*)bias + d0);
    float bv[4] = {bfu(bb.x), bfu(bb.y), bfu(bb.z), bfu(bb.w)};
    #pragma unroll
    for (int r = 0; r < 4; ++r) {
        deltaT[(size_t)(d0 + r) * ROWS + n0 + m16] = softplus_f(acc[r] + bv[r]);
    }
}

// sum the two split-K partials, store to d_out as bf16 or f32 per flag
__global__ __launch_bounds__(256) void sum_store(
    const float* __restrict__ p0, const float* __restrict__ p1,
    void* __restrict__ out, const int* __restrict__ flag, int n4)
{
    int i = blockIdx.x * 256 + threadIdx.x;
    if (i >= n4) return;
    float4 a = ((const float4*)p0)[i];
    float4 b = ((const float4*)p1)[i];
    float4 sv; sv.x = a.x + b.x; sv.y = a.y + b.y; sv.z = a.z + b.z; sv.w = a.w + b.w;
    if (*flag) {
        ushort4 o;
        o.x = bf_bits(sv.x); o.y = bf_bits(sv.y);
        o.z = bf_bits(sv.z); o.w = bf_bits(sv.w);
        ((ushort4*)out)[i] = o;
    } else {
        ((float4*)out)[i] = sv;
    }
}

// ---------------- transpose (d,row) -> (row,d), 64x64 LDS tiles ----------------
__global__ __launch_bounds__(256) void transpose_bf16(
    const ushort* __restrict__ src,   // (DINNER, ROWS)
    ushort* __restrict__ dst)         // (ROWS, DINNER)
{
    __shared__ ushort t[64][65];
    const int bx = blockIdx.x;        // row-tile
    const int by = blockIdx.y;        // d-tile
    const int tid = threadIdx.x;
    const int lr = tid & 63;
    const int ld = tid >> 6;          // 0..3
    #pragma unroll
    for (int i = 0; i < 16; ++i) {
        int d = ld + i * 4;
        t[d][lr] = src[(size_t)(by * 64 + d) * ROWS + bx * 64 + lr];
    }
    __syncthreads();
    #pragma unroll
    for (int i = 0; i < 16; ++i) {
        int r = ld + i * 4;
        dst[(size_t)(bx * 64 + r) * DINNER + by * 64 + lr] = t[lr][r];
    }
}

// ---------------- xd cvt: xd (2048,96) f32 -> xd_bf bf16 (row-major) ----------------
__global__ __launch_bounds__(256) void xd_cvt(
    const float* __restrict__ xd,
    bf16* __restrict__ xd_bf)
{
    int i = blockIdx.x * 256 + threadIdx.x;   // float4 index; grid sized exactly
    float4 v = ((const float4*)xd)[i];
    ushort4 o;
    o.x = bf_bits(v.x); o.y = bf_bits(v.y);
    o.z = bf_bits(v.z); o.w = bf_bits(v.w);
    ((ushort4*)xd_bf)[i] = o;
}

// ---------------- fused conv+silu+transpose: xzT -> utT (d-major) AND ut (row-major) ----
__global__ __launch_bounds__(256) void conv_silu_fused(
    const bf16* __restrict__ xzT,   // (4096, ROWS); x part rows 0..DINNER-1
    const bf16* __restrict__ w,     // (DINNER, 4)
    const bf16* __restrict__ bias,  // (DINNER,)
    bf16* __restrict__ utT,         // (DINNER, ROWS)
    ushort* __restrict__ ut)        // (ROWS, DINNER)
{
    __shared__ ushort sx[64][68];   // [d-local][r-local+4 halo]
    __shared__ ushort tt[64][65];   // staged outputs for the transpose write
    const int bx = blockIdx.x;      // r tile
    const int by = blockIdx.y;      // d tile
    const int tid = threadIdx.x;
    const int gr0 = bx * 64;
    const bool seqstart = (bx & 15) == 0;   // tile starts a sequence (r0 = 0 or 1024)

    // load 64 rows x 17 ushort4 chunks (cols gr0-4 .. gr0+63)
    for (int idx = tid; idx < 64 * 17; idx += 256) {
        int row = idx / 17;
        int c = idx - row * 17;
        ushort4 v;
        if (c == 0 && seqstart) {
            v.x = v.y = v.z = v.w = 0;   // pre-sequence halo = 0 (no OOB read)
        } else {
            const ushort* src = (const ushort*)xzT +
                (size_t)(by * 64 + row) * ROWS + (gr0 - 4 + c * 4);
            v = *(const ushort4*)src;
        }
        *(ushort4*)&sx[row][c * 4] = v;
    }
    __syncthreads();

    const int lr = tid & 63;        // r-local (per-lane)
    const int ld = tid >> 6;        // wave id 0..3 (wave-uniform)
    #pragma unroll
    for (int i = 0; i < 16; ++i) {
        int dl = ld + i * 4;        // wave-uniform d-local
        int dg = by * 64 + dl;
        ushort4 wv = *(const ushort4*)((const ushort*)w + dg * 4);  // scalarized
        float w0 = bfu(wv.x), w1 = bfu(wv.y), w2 = bfu(wv.z), w3 = bfu(wv.w);
        float bv = to_f(bias[dg]);
        float acc = bv;
        acc = fmaf(bfu(sx[dl][lr + 1]), w0, acc);   // x[r-3]
        acc = fmaf(bfu(sx[dl][lr + 2]), w1, acc);   // x[r-2]
        acc = fmaf(bfu(sx[dl][lr + 3]), w2, acc);   // x[r-1]
        acc = fmaf(bfu(sx[dl][lr + 4]), w3, acc);   // x[r]
        ushort o = bf_bits(silu_f(acc));
        ((ushort*)utT)[(size_t)dg * ROWS + gr0 + lr] = o;
        tt[dl][lr] = o;
    }
    __syncthreads();
    #pragma unroll
    for (int i = 0; i < 16; ++i) {
        int rl = ld + i * 4;
        ut[(size_t)(gr0 + rl) * DINNER + by * 64 + lr] = tt[lr][rl];
    }
}

// ---------------- scan v16: cheap-pass / full-pass, 512-thr wave-uniform chunks ----
#define SCHUNK 8
#define SSTEPS (SEQLEN / SCHUNK)   // 128
__global__ __launch_bounds__(512) void scan_kernel16(
    const float* __restrict__ deltaT,  // (DINNER, ROWS) f32
    const bf16*  __restrict__ utT,     // (DINNER, ROWS)
    const float* __restrict__ xd96,    // (ROWS, 96) f32: col 64+n = B_n, 80+n = C_n
    const bf16*  __restrict__ xzT,     // (4096, ROWS): z at row DINNER+d
    const bf16*  __restrict__ A_log,   // (DINNER,16)
    const bf16*  __restrict__ Dp,      // (DINNER,)
    bf16* __restrict__ outzT)          // (DINNER, ROWS)
{
    __shared__ float2 sHP[SCHUNK][64];
    const int tid = threadIdx.x;
    const int c = tid >> 6;            // wave-uniform chunk id 0..7
    const int w = tid & 63;
    const int dcol = (tid >> 4) & 3;
    const int n = tid & 15;
    const int b = blockIdx.x >> 9;
    const int d = ((blockIdx.x & 511) << 2) + dcol;
    const int row0 = b * SEQLEN + c * SSTEPS;

    const float Aa2 = -expf(to_f(A_log[d * DSTATE + n])) * LOG2E;
    const float Dv = to_f(Dp[d]);

    const float*  dp = deltaT + (size_t)d * ROWS + row0;
    const ushort* up = (const ushort*)utT + (size_t)d * ROWS + row0;
    const ushort* zp = (const ushort*)xzT + (size_t)(DINNER + d) * ROWS + row0;
    const float*  bcp = xd96 + (size_t)row0 * 96 + 64 + n;  // B at +0, C at +16

    // ---- pass A: chunk summary only (h-chain + sum of delta) ----
    // NOTE: dv/uv last-iteration prefetch reads 16B past the logical chunk;
    // all streams are interior workspace regions followed by more workspace,
    // so the over-read stays inside d_ws and the values are never used.
    float hl = 0.f, sd = 0.f;
    float4  dv4 = *(const float4*)(dp);
    ushort4 uv4 = *(const ushort4*)(up);
    const float* bct = bcp;
    for (int i0 = 0; i0 < SSTEPS; i0 += 4) {
        float4  dvn = *(const float4*)(dp + i0 + 4);
        ushort4 uvn = *(const ushort4*)(up + i0 + 4);
        float Bv[4];
        Bv[0] = bct[0];
        Bv[1] = bct[96];
        Bv[2] = bct[192];
        Bv[3] = bct[288];
        bct += 384;
        float dv[4] = {dv4.x, dv4.y, dv4.z, dv4.w};
        float uv[4] = {bfu(uv4.x), bfu(uv4.y), bfu(uv4.z), bfu(uv4.w)};
        #pragma unroll
        for (int j = 0; j < 4; ++j) {
            sd += dv[j];
            float a = fexp2(dv[j] * Aa2);
            hl = fmaf(a, hl, dv[j] * Bv[j] * uv[j]);
        }
        dv4 = dvn; uv4 = uvn;
    }
    sHP[c][w] = make_float2(hl, fexp2(sd * Aa2));
    __syncthreads();

    // ---- fold preceding chunk summaries (<= 7 iters, wave-uniform) ----
    float hin = 0.f;
    for (int cc = 0; cc < c; ++cc) {
        float2 hp = sHP[cc][w];
        hin = fmaf(hp.y, hin, hp.x);
    }

    // ---- pass B: full rescan seeded with hin; y produced directly ----
    float h = hin;
    dv4 = *(const float4*)(dp);
    uv4 = *(const ushort4*)(up);
    ushort4 zv4 = *(const ushort4*)(zp);
    bct = bcp;
    for (int i0 = 0; i0 < SSTEPS; i0 += 4) {
        float4  dvn = *(const float4*)(dp + i0 + 4);
        ushort4 uvn = *(const ushort4*)(up + i0 + 4);
        ushort4 zvn = *(const ushort4*)(zp + i0 + 4);
        float Bv[4], Cv[4];
        Bv[0] = bct[0];   Cv[0] = bct[16];
        Bv[1] = bct[96];  Cv[1] = bct[112];
        Bv[2] = bct[192]; Cv[2] = bct[208];
        Bv[3] = bct[288]; Cv[3] = bct[304];
        bct += 384;
        float dv[4] = {dv4.x, dv4.y, dv4.z, dv4.w};
        float uv[4] = {bfu(uv4.x), bfu(uv4.y), bfu(uv4.z), bfu(uv4.w)};
        float zv[4] = {bfu(zv4.x), bfu(zv4.y), bfu(zv4.z), bfu(zv4.w)};
        float y[4];
        #pragma unroll
        for (int j = 0; j < 4; ++j) {
            float a = fexp2(dv[j] * Aa2);
            h = fmaf(a, h, dv[j] * Bv[j] * uv[j]);
            float p = h * Cv[j];
            p = row16_sum_to_lane15(p);
            y[j] = fmaf(uv[j], Dv, p);
        }
        if (n == 15) {
            ushort4 o;
            o.x = bf_bits(y[0] * silu_f(zv[0]));
            o.y = bf_bits(y[1] * silu_f(zv[1]));
            o.z = bf_bits(y[2] * silu_f(zv[2]));
            o.w = bf_bits(y[3] * silu_f(zv[3]));
            *(ushort4*)((ushort*)outzT + (size_t)d * ROWS + row0 + i0) = o;
        }
        dv4 = dvn; uv4 = uvn; zv4 = zvn;
    }
}

extern "C" void kernel_launch(void* const* d_in, const int* in_sizes, int n_in,
                              void* d_out, int out_size, void* d_ws, size_t ws_size,
                              hipStream_t stream) {
    static const size_t SZ[10] = {
        (size_t)BATCH * SEQLEN * DMODEL,        // hidden_states
        (size_t)2 * DINNER * DMODEL,            // in_proj_w
        (size_t)DINNER * 4,                     // conv1d_w
        (size_t)DINNER,                         // conv1d_b
        (size_t)(DTRANK + 2 * DSTATE) * DINNER, // x_proj_w
        (size_t)DINNER * DTRANK,                // dt_proj_w
        (size_t)DINNER,                         // dt_proj_b
        (size_t)DINNER * DSTATE,                // A_log
        (size_t)DINNER,                         // D_param
        (size_t)DMODEL * DINNER                 // out_proj_w
    };
    size_t tot_in = 0;
    for (int i = 0; i < 10; ++i) tot_in += SZ[i];

    char* p = (char*)d_ws;
    int* flag = (int*)p;                     p += 64;
    bf16* inb = (bf16*)p;                    p += tot_in * 2;
    bf16* xzT = (bf16*)p;                    p += (size_t)4096 * ROWS * 2;
    bf16* utT = (bf16*)p;                    p += (size_t)DINNER * ROWS * 2;
    bf16* ut  = (bf16*)p;                    p += (size_t)ROWS * DINNER * 2;
    float* xd = (float*)p;                   p += (size_t)ROWS * 96 * 4;
    bf16* xd_bf = (bf16*)p;                  p += (size_t)ROWS * 96 * 2;
    float* deltaT = (float*)p;               p += (size_t)DINNER * ROWS * 4;
    bf16* outzT = (bf16*)p;                  p += (size_t)DINNER * ROWS * 2;
    bf16* outz = (bf16*)p;                   p += (size_t)ROWS * DINNER * 2;
    float* part = (float*)p;                 p += (size_t)2 * ROWS * DMODEL * 4;
    size_t needed = (size_t)(p - (char*)d_ws);
    if (ws_size < needed) return;

    dim3 blk(256);

    // 0) detect dtype + zero xd (for atomic accumulation)
    prep_kernel<<<1 + (ROWS * 96 + 255) / 256, blk, 0, stream>>>(
        (const unsigned short*)d_in[0], flag, xd, ROWS * 96);

    bf16* inp[10];
    {
        size_t off = 0;
        for (int i = 0; i < 10; ++i) { inp[i] = inb + off; off += SZ[i]; }
    }
    SrcPtrs sp;
    for (int i = 0; i < 10; ++i) sp.p[i] = d_in[i];
    convert_all<<<(int)((tot_in / 4 + 255) / 256), blk, 0, stream>>>(sp, inb, flag);

    const bf16* hs        = inp[0];
    const bf16* in_proj_w = inp[1];
    const bf16* conv_w    = inp[2];
    const bf16* conv_b    = inp[3];
    const bf16* x_proj_w  = inp[4];
    const bf16* dt_proj_w = inp[5];
    const bf16* dt_proj_b = inp[6];
    const bf16* A_log     = inp[7];
    const bf16* Dp        = inp[8];
    const bf16* out_proj_w= inp[9];

    // 1) xzT = (hs @ in_proj_w^T)^T : dual-ptr — reads d_in directly when bf16
    gemm_mfma<0><<<dim3(ROWS / 128, 4096 / 128, 1), blk, 0, stream>>>(
        in_proj_w, DMODEL, hs, DMODEL, xzT, ROWS, DMODEL, 0, nullptr,
        (const bf16*)d_in[1], (const bf16*)d_in[0], flag);

    // 2) fused: utT = silu(causal conv along L) AND ut = utT^T, one pass
    conv_silu_fused<<<dim3(ROWS / 64, DINNER / 64), blk, 0, stream>>>(
        xzT, conv_w, conv_b, utT, (ushort*)ut);

    // 3) xd[row][r] = sum_d ut[row][d] * x_proj_w[r][d]  (MFMA, split-K=4, atomic f32)
    gemm_mfma<3><<<dim3(1, ROWS / 128, 4), blk, 0, stream>>>(
        ut, DINNER, x_proj_w, DINNER, xd, 96, DINNER / 4, 0, nullptr,
        nullptr, nullptr, nullptr);

    // 3b) xd_bf = bf16(xd)  (row-major, dt GEMM operand); scan reads xd directly
    xd_cvt<<<ROWS * 96 / 4 / 256, blk, 0, stream>>>(xd, xd_bf);

    // 4) deltaT = softplus(xd_bf[:, :64] @ dtw^T + b)  — custom no-LDS 16x16 MFMA
    dt_gemm<<<dim3(ROWS / 16, DINNER / 64), blk, 0, stream>>>(
        dt_proj_w, xd_bf, dt_proj_b, deltaT);

    // 5) chunk-parallel selective scan -> outzT (d-major, full-line writes)
    scan_kernel16<<<BATCH * (DINNER / 4), dim3(512), 0, stream>>>(
        deltaT, utT, xd, xzT, A_log, Dp, outzT);

    // 5b) outz = outzT^T (row-major for gemm6)
    transpose_bf16<<<dim3(ROWS / 64, DINNER / 64), blk, 0, stream>>>(
        (const ushort*)outzT, (ushort*)outz);

    // 6) out = outz @ out_proj_w^T  (MFMA split-K=2 -> f32 partials; dual-ptr B)
    gemm_mfma<2><<<dim3(DMODEL / 128, ROWS / 128, 2), blk, 0, stream>>>(
        outz, DINNER, out_proj_w, DINNER, part, DMODEL, DINNER / 2, (size_t)ROWS * DMODEL,
        nullptr, nullptr, (const bf16*)d_in[9], flag);

    // 6b) out = cvt(part0 + part1)
    sum_store<<<(ROWS * DMODEL / 4 + 255) / 256, blk, 0, stream>>>(
        part, part + (size_t)ROWS * DMODEL, d_out, flag, ROWS * DMODEL / 4);
}